// Round 3
// baseline (178.029 us; speedup 1.0000x reference)
//
#include <hip/hip_runtime.h>
#include <hip/hip_bf16.h>

#define NN 50000
#define NE 800000

// ---------------- k0: pack KAN weights: Wk[o][i*6+c] = {base_w[o][i], spline_w[o][i][k]*scaler[o][i]}
__global__ __launch_bounds__(256) void k0_pack(
    const float* __restrict__ base_w, const float* __restrict__ spline_w,
    const float* __restrict__ scaler, float* __restrict__ Wk) {
  int idx = blockIdx.x * 256 + threadIdx.x;  // o*64 + i
  if (idx >= 64 * 64) return;
  float sc = scaler[idx];
  float* dst = Wk + (size_t)(idx >> 6) * 384 + (size_t)(idx & 63) * 6;
  dst[0] = base_w[idx];
#pragma unroll
  for (int k = 0; k < 5; ++k) dst[1 + k] = spline_w[(size_t)idx * 5 + k] * sc;
}

// ---------------- k_off: CSR offsets from sorted seg_ids. off[n] = first edge with seg >= n.
__global__ __launch_bounds__(256) void k_off(const int* __restrict__ seg, int* __restrict__ off) {
  int e = blockIdx.x * 256 + threadIdx.x;
  if (e >= NE) return;
  int s1 = seg[e];
  if (e == 0) {
    for (int n = 0; n <= s1; ++n) off[n] = 0;
  } else {
    int s0 = seg[e - 1];
    for (int n = s0 + 1; n <= s1; ++n) off[n] = e;
  }
  if (e == NE - 1) {
    for (int n = s1 + 1; n <= NN; ++n) off[n] = NE;
  }
}

// ---------------- k1: per-node edge aggregation. One wave per node, 16 edges per iteration.
// Sp[n][f] = (sum_e attn_e * ctx_e[f]) / max(deg,1);  aprime[n] = (sum attn)/max(deg,1); degw[n]=deg
__global__ __launch_bounds__(1024) void k1_edge_agg(
    const float* __restrict__ contexts, const float* __restrict__ attn,
    const int* __restrict__ off, float* __restrict__ Sp,
    float* __restrict__ aprime, float* __restrict__ degw) {
  int n = blockIdx.x * 16 + (threadIdx.x >> 6);
  int lane = threadIdx.x & 63;
  if (n >= NN) return;
  int s = off[n];
  int e_end = off[n + 1];
  int deg_i = e_end - s;

  int sub = lane >> 4;   // which edge within a quad
  int fq = lane & 15;    // feature quad (4 floats)
  const float4* ctx4 = (const float4*)contexts;

  float4 S = make_float4(0.f, 0.f, 0.f, 0.f);
  float A = 0.f;
  if (deg_i > 0) {
    int last = e_end - 1;
    for (int e0 = s; e0 < e_end; e0 += 16) {
      float a[4];
      float4 c[4];
#pragma unroll
      for (int u = 0; u < 4; ++u) {
        int eu = e0 + 4 * u + sub;
        a[u] = (eu < e_end) ? attn[eu] : 0.f;
        c[u] = ctx4[(size_t)min(eu, last) * 16 + fq];
      }
#pragma unroll
      for (int u = 0; u < 4; ++u) {
        S.x += a[u] * c[u].x;
        S.y += a[u] * c[u].y;
        S.z += a[u] * c[u].z;
        S.w += a[u] * c[u].w;
        A += a[u];
      }
    }
  }
  // reduce across the 4 subgroups (xor 16, 32)
#pragma unroll
  for (int m = 16; m <= 32; m <<= 1) {
    S.x += __shfl_xor(S.x, m);
    S.y += __shfl_xor(S.y, m);
    S.z += __shfl_xor(S.z, m);
    S.w += __shfl_xor(S.w, m);
    A += __shfl_xor(A, m);
  }
  float deg = (float)deg_i;
  float inv = 1.f / fmaxf(deg, 1.f);
  if (lane < 16) {
    float4 o = make_float4(S.x * inv, S.y * inv, S.z * inv, S.w * inv);
    ((float4*)Sp)[(size_t)n * 16 + lane] = o;
  }
  if (lane == 0) { aprime[n] = A * inv; degw[n] = deg; }
}

// ---------------- k234: fused t-GEMM + upd-GEMM + KAN head for a 64-node tile.
// LDS arena (16896 floats = 67.6 KB), phase-overlaid:
//   phase A/B: uS  = sm[0..8447]      [64][132]  (x | Sp)
//              tlS = sm[8448..16895]  [64][132]  (t)
//   phase C:   updT= sm[0..4351]      [64][68]   (upd)
//   phase D:   vS  = sm[4352..16767]  [32][388]  (KAN features, per 32-node half)
//              otS = sm[4352..6527]   [32][68]   (out tile, after GEMM)
__global__ __launch_bounds__(256) void k234(
    const float* __restrict__ x, const float* __restrict__ Sp,
    const float* __restrict__ aprime, const float* __restrict__ degw,
    const float* __restrict__ Wn, const float* __restrict__ bn,
    const float* __restrict__ Wc, const float* __restrict__ bc,
    const float* __restrict__ Wu, const float* __restrict__ bu,
    const float* __restrict__ Wk, const float* __restrict__ gridp,
    float* __restrict__ out) {
  __shared__ __align__(16) float sm[16896];
  __shared__ float ap[64], degl[64];
  float* uS = sm;            // [64][132]
  float* tlS = sm + 8448;    // [64][132]
  float* updT = sm;          // [64][68]
  float* vS = sm + 4352;     // [32][388]
  float* otS = sm + 4352;    // [32][68]

  int tid = threadIdx.x;
  int n0 = blockIdx.x * 64;

  // ---- phase A: stage [x|Sp] tile + ap + degl
  for (int q = tid; q < 64 * 32; q += 256) {
    int b = q >> 5, c = q & 31;
    int n = n0 + b;
    float4 val = make_float4(0.f, 0.f, 0.f, 0.f);
    if (n < NN) {
      if (c < 16) val = *(const float4*)(x + (size_t)n * 64 + c * 4);
      else        val = *(const float4*)(Sp + (size_t)n * 64 + (c - 16) * 4);
    }
    *(float4*)&uS[b * 132 + c * 4] = val;
  }
  if (tid < 64) {
    int n = n0 + tid;
    ap[tid] = (n < NN) ? aprime[n] : 0.f;
    degl[tid] = (n < NN) ? degw[n] : 1.f;
  }
  __syncthreads();

  int wv = tid >> 6, lane = tid & 63;
  int nm = lane & 7, nh = lane >> 3;

  // ---- phase B: t = [x|Sp] @ [Wn|Wc]^T + bn + a'*bc   (K=128)
  {
    float acc[8][4];
#pragma unroll
    for (int i = 0; i < 8; ++i)
#pragma unroll
      for (int j = 0; j < 4; ++j) acc[i][j] = 0.f;
    const float4* Wn4 = (const float4*)Wn;
    const float4* Wc4 = (const float4*)Wc;
    int hbase = wv * 32 + nh * 4;
#pragma unroll 4
    for (int fb = 0; fb < 16; ++fb) {  // x part vs Wn
      float4 w[4];
#pragma unroll
      for (int j = 0; j < 4; ++j) w[j] = Wn4[(size_t)(hbase + j) * 16 + fb];
#pragma unroll
      for (int i = 0; i < 8; ++i) {
        float4 uv = *(const float4*)&uS[(nm + 8 * i) * 132 + fb * 4];
#pragma unroll
        for (int j = 0; j < 4; ++j)
          acc[i][j] += uv.x * w[j].x + uv.y * w[j].y + uv.z * w[j].z + uv.w * w[j].w;
      }
    }
#pragma unroll 4
    for (int fb = 0; fb < 16; ++fb) {  // Sp part vs Wc
      float4 w[4];
#pragma unroll
      for (int j = 0; j < 4; ++j) w[j] = Wc4[(size_t)(hbase + j) * 16 + fb];
#pragma unroll
      for (int i = 0; i < 8; ++i) {
        float4 uv = *(const float4*)&uS[(nm + 8 * i) * 132 + 64 + fb * 4];
#pragma unroll
        for (int j = 0; j < 4; ++j)
          acc[i][j] += uv.x * w[j].x + uv.y * w[j].y + uv.z * w[j].z + uv.w * w[j].w;
      }
    }
#pragma unroll
    for (int j = 0; j < 4; ++j) {
      int h = hbase + j;
      float bnv = bn[h], bcv = bc[h];
#pragma unroll
      for (int i = 0; i < 8; ++i) {
        int b = nm + 8 * i;
        tlS[b * 132 + h] = acc[i][j] + bnv + ap[b] * bcv;
      }
    }
  }
  __syncthreads();

  // ---- phase C: upd = t @ Wu^T + bu  (K=128) -> updT (overlays dead uS)
  {
    float acc[8][2];
#pragma unroll
    for (int i = 0; i < 8; ++i) { acc[i][0] = 0.f; acc[i][1] = 0.f; }
    const float4* Wu4 = (const float4*)Wu;
    int obase = wv * 16 + nh * 2;
#pragma unroll 4
    for (int fb = 0; fb < 32; ++fb) {
      float4 w[2];
#pragma unroll
      for (int j = 0; j < 2; ++j) w[j] = Wu4[(size_t)(obase + j) * 32 + fb];
#pragma unroll
      for (int i = 0; i < 8; ++i) {
        float4 tv = *(const float4*)&tlS[(nm + 8 * i) * 132 + fb * 4];
#pragma unroll
        for (int j = 0; j < 2; ++j)
          acc[i][j] += tv.x * w[j].x + tv.y * w[j].y + tv.z * w[j].z + tv.w * w[j].w;
      }
    }
#pragma unroll
    for (int j = 0; j < 2; ++j) {
      int o = obase + j;
      float buv = bu[o];
#pragma unroll
      for (int i = 0; i < 8; ++i) {
        int b = nm + 8 * i;
        updT[b * 68 + o] = acc[i][j] + buv;
      }
    }
  }
  __syncthreads();

  // ---- phase D: KAN head in two 32-node halves
  float g[8];
#pragma unroll
  for (int j = 0; j < 8; ++j) g[j] = gridp[j];  // all grid rows identical
  float r1[7], r2[6];
#pragma unroll
  for (int j = 0; j < 7; ++j) r1[j] = 1.f / (g[j + 1] - g[j]);
#pragma unroll
  for (int j = 0; j < 6; ++j) r2[j] = 1.f / (g[j + 2] - g[j]);
  const float4* Wk4 = (const float4*)Wk;

  for (int h = 0; h < 2; ++h) {
    // transform upd -> v (silu + order-2 spline bases), 32 nodes
    for (int q = tid; q < 32 * 64; q += 256) {
      int b = q >> 6, i = q & 63;
      float xv = updT[(h * 32 + b) * 68 + i];
      float sil = xv / (1.f + __expf(-xv));
      float b0[7], b1[6], b2[5];
#pragma unroll
      for (int j = 0; j < 7; ++j) b0[j] = (xv >= g[j] && xv < g[j + 1]) ? 1.f : 0.f;
#pragma unroll
      for (int j = 0; j < 6; ++j)
        b1[j] = (xv - g[j]) * r1[j] * b0[j] + (g[j + 2] - xv) * r1[j + 1] * b0[j + 1];
#pragma unroll
      for (int j = 0; j < 5; ++j)
        b2[j] = (xv - g[j]) * r2[j] * b1[j] + (g[j + 3] - xv) * r2[j + 1] * b1[j + 1];
      float* dst = &vS[b * 388 + i * 6];
      dst[0] = sil;
#pragma unroll
      for (int k = 0; k < 5; ++k) dst[1 + k] = b2[k];
    }
    __syncthreads();

    // GEMM: out = v @ Wk^T  (K=384)
    float acc[4][2];
#pragma unroll
    for (int i = 0; i < 4; ++i) { acc[i][0] = 0.f; acc[i][1] = 0.f; }
    int obase = wv * 16 + nh * 2;
#pragma unroll 4
    for (int kb = 0; kb < 96; ++kb) {
      float4 w[2];
#pragma unroll
      for (int j = 0; j < 2; ++j) w[j] = Wk4[(size_t)(obase + j) * 96 + kb];
#pragma unroll
      for (int i = 0; i < 4; ++i) {
        float4 vv = *(const float4*)&vS[(nm + 8 * i) * 388 + kb * 4];
#pragma unroll
        for (int j = 0; j < 2; ++j)
          acc[i][j] += vv.x * w[j].x + vv.y * w[j].y + vv.z * w[j].z + vv.w * w[j].w;
      }
    }
    __syncthreads();  // vS dead; reuse as out tile

    // epilogue: deg fallback + stage out tile
#pragma unroll
    for (int j = 0; j < 2; ++j) {
#pragma unroll
      for (int i = 0; i < 4; ++i) {
        int b = nm + 8 * i, o = obase + j;
        float val = acc[i][j];
        if (degl[h * 32 + b] <= 0.f) {
          int n = n0 + h * 32 + b;
          if (n < NN) val = x[(size_t)n * 64 + o];
        }
        otS[b * 68 + o] = val;
      }
    }
    __syncthreads();

    // coalesced store of 32x64 out tile
    for (int q = tid; q < 32 * 64; q += 256) {
      int b = q >> 6, o = q & 63;
      int n = n0 + h * 32 + b;
      if (n < NN) out[(size_t)n * 64 + o] = otS[b * 68 + o];
    }
    __syncthreads();
  }
}

extern "C" void kernel_launch(void* const* d_in, const int* in_sizes, int n_in,
                              void* d_out, int out_size, void* d_ws, size_t ws_size,
                              hipStream_t stream) {
  const float* x        = (const float*)d_in[0];
  const float* contexts = (const float*)d_in[1];
  const float* attn     = (const float*)d_in[2];
  const int*   seg      = (const int*)d_in[3];
  const float* Wn       = (const float*)d_in[4];
  const float* bn       = (const float*)d_in[5];
  const float* Wc       = (const float*)d_in[6];
  const float* bc       = (const float*)d_in[7];
  const float* Wu       = (const float*)d_in[8];
  const float* bu       = (const float*)d_in[9];
  const float* base_w   = (const float*)d_in[10];
  const float* spline_w = (const float*)d_in[11];
  const float* scaler   = (const float*)d_in[12];
  const float* gridp    = (const float*)d_in[13];
  float* out = (float*)d_out;

  float* ws     = (float*)d_ws;
  float* Sp     = ws;                  // N*64
  float* aprime = Sp + 3200000;        // N
  float* degw   = aprime + 50000;      // N
  float* Wk     = degw + 50000;        // 64*384 = 24576
  int*   off    = (int*)(Wk + 24576);  // N+1

  k0_pack<<<16, 256, 0, stream>>>(base_w, spline_w, scaler, Wk);
  k_off<<<3125, 256, 0, stream>>>(seg, off);
  k1_edge_agg<<<3125, 1024, 0, stream>>>(contexts, attn, off, Sp, aprime, degw);
  k234<<<782, 256, 0, stream>>>(x, Sp, aprime, degw, Wn, bn, Wc, bc, Wu, bu, Wk, gridp, out);
}

// Round 4
// 175.172 us; speedup vs baseline: 1.0163x; 1.0163x over previous
//
#include <hip/hip_runtime.h>
#include <hip/hip_bf16.h>

#define NN 50000
#define NE 800000

// ---------------- k0: pack KAN weights: Wk[o][i*6+c] = {base_w[o][i], spline_w[o][i][k]*scaler[o][i]}
__global__ __launch_bounds__(256) void k0_pack(
    const float* __restrict__ base_w, const float* __restrict__ spline_w,
    const float* __restrict__ scaler, float* __restrict__ Wk) {
  int idx = blockIdx.x * 256 + threadIdx.x;  // o*64 + i
  if (idx >= 64 * 64) return;
  float sc = scaler[idx];
  float* dst = Wk + (size_t)(idx >> 6) * 384 + (size_t)(idx & 63) * 6;
  dst[0] = base_w[idx];
#pragma unroll
  for (int k = 0; k < 5; ++k) dst[1 + k] = spline_w[(size_t)idx * 5 + k] * sc;
}

// ---------------- k_off: CSR offsets from sorted seg_ids. off[n] = first edge with seg >= n.
__global__ __launch_bounds__(256) void k_off(const int* __restrict__ seg, int* __restrict__ off) {
  int e = blockIdx.x * 256 + threadIdx.x;
  if (e >= NE) return;
  int s1 = seg[e];
  if (e == 0) {
    for (int n = 0; n <= s1; ++n) off[n] = 0;
  } else {
    int s0 = seg[e - 1];
    for (int n = s0 + 1; n <= s1; ++n) off[n] = e;
  }
  if (e == NE - 1) {
    for (int n = s1 + 1; n <= NN; ++n) off[n] = NE;
  }
}

// ---------------- k1: per-node edge aggregation. One wave per node, 16 edges per iteration.
// Sp[n][f] = (sum_e attn_e * ctx_e[f]) / max(deg,1);  aprime[n] = (sum attn)/max(deg,1); degw[n]=deg
__global__ __launch_bounds__(1024) void k1_edge_agg(
    const float* __restrict__ contexts, const float* __restrict__ attn,
    const int* __restrict__ off, float* __restrict__ Sp,
    float* __restrict__ aprime, float* __restrict__ degw) {
  int n = blockIdx.x * 16 + (threadIdx.x >> 6);
  int lane = threadIdx.x & 63;
  if (n >= NN) return;
  int s = off[n];
  int e_end = off[n + 1];
  int deg_i = e_end - s;

  int sub = lane >> 4;   // which edge within a quad
  int fq = lane & 15;    // feature quad (4 floats)
  const float4* ctx4 = (const float4*)contexts;

  float4 S = make_float4(0.f, 0.f, 0.f, 0.f);
  float A = 0.f;
  if (deg_i > 0) {
    int last = e_end - 1;
    for (int e0 = s; e0 < e_end; e0 += 16) {
      float a[4];
      float4 c[4];
#pragma unroll
      for (int u = 0; u < 4; ++u) {
        int eu = e0 + 4 * u + sub;
        a[u] = (eu < e_end) ? attn[eu] : 0.f;
        c[u] = ctx4[(size_t)min(eu, last) * 16 + fq];
      }
#pragma unroll
      for (int u = 0; u < 4; ++u) {
        S.x += a[u] * c[u].x;
        S.y += a[u] * c[u].y;
        S.z += a[u] * c[u].z;
        S.w += a[u] * c[u].w;
        A += a[u];
      }
    }
  }
  // reduce across the 4 subgroups (xor 16, 32)
#pragma unroll
  for (int m = 16; m <= 32; m <<= 1) {
    S.x += __shfl_xor(S.x, m);
    S.y += __shfl_xor(S.y, m);
    S.z += __shfl_xor(S.z, m);
    S.w += __shfl_xor(S.w, m);
    A += __shfl_xor(A, m);
  }
  float deg = (float)deg_i;
  float inv = 1.f / fmaxf(deg, 1.f);
  if (lane < 16) {
    float4 o = make_float4(S.x * inv, S.y * inv, S.z * inv, S.w * inv);
    ((float4*)Sp)[(size_t)n * 16 + lane] = o;
  }
  if (lane == 0) { aprime[n] = A * inv; degw[n] = deg; }
}

// ---------------- k23: t = [x|Sp] @ [Wn|Wc]^T + bn + a'*bc ; upd = t @ Wu^T + bu
// 64-node tile per block, 256 threads (4 waves). Wave w computes h in [w*32,(w+1)*32) then o in [w*16,(w+1)*16).
__global__ __launch_bounds__(256) void k23_gemm(
    const float* __restrict__ x, const float* __restrict__ Sp,
    const float* __restrict__ aprime,
    const float* __restrict__ Wn, const float* __restrict__ bn,
    const float* __restrict__ Wc, const float* __restrict__ bc,
    const float* __restrict__ Wu, const float* __restrict__ bu,
    float* __restrict__ upd) {
  __shared__ __align__(16) float u[64][132];   // [node][f 0..127], f<64: x, f>=64: Sp
  __shared__ __align__(16) float tl[64][132];  // [node][h 0..127]
  __shared__ float ap[64];
  int tid = threadIdx.x;
  int n0 = blockIdx.x * 64;

  // stage u tile (float4)
  for (int q = tid; q < 64 * 32; q += 256) {
    int b = q >> 5, c = q & 31;
    int n = n0 + b;
    float4 val = make_float4(0.f, 0.f, 0.f, 0.f);
    if (n < NN) {
      if (c < 16) val = *(const float4*)(x + (size_t)n * 64 + c * 4);
      else        val = *(const float4*)(Sp + (size_t)n * 64 + (c - 16) * 4);
    }
    *(float4*)&u[b][c * 4] = val;
  }
  if (tid < 64) {
    int n = n0 + tid;
    ap[tid] = (n < NN) ? aprime[n] : 0.f;
  }
  __syncthreads();

  int wv = tid >> 6, lane = tid & 63;
  int nm = lane & 7, nh = lane >> 3;

  // ---- t-GEMM: acc[8 nodes][4 h], K=128
  {
    float acc[8][4];
#pragma unroll
    for (int i = 0; i < 8; ++i)
#pragma unroll
      for (int j = 0; j < 4; ++j) acc[i][j] = 0.f;
    const float4* Wn4 = (const float4*)Wn;
    const float4* Wc4 = (const float4*)Wc;
    int hbase = wv * 32 + nh * 4;
#pragma unroll 4
    for (int fb = 0; fb < 16; ++fb) {  // f = fb*4 in [0,64): x part vs Wn
      float4 w[4];
#pragma unroll
      for (int j = 0; j < 4; ++j) w[j] = Wn4[(size_t)(hbase + j) * 16 + fb];
#pragma unroll
      for (int i = 0; i < 8; ++i) {
        float4 uv = *(const float4*)&u[nm + 8 * i][fb * 4];
#pragma unroll
        for (int j = 0; j < 4; ++j)
          acc[i][j] += uv.x * w[j].x + uv.y * w[j].y + uv.z * w[j].z + uv.w * w[j].w;
      }
    }
#pragma unroll 4
    for (int fb = 0; fb < 16; ++fb) {  // f = 64 + fb*4: Sp part vs Wc
      float4 w[4];
#pragma unroll
      for (int j = 0; j < 4; ++j) w[j] = Wc4[(size_t)(hbase + j) * 16 + fb];
#pragma unroll
      for (int i = 0; i < 8; ++i) {
        float4 uv = *(const float4*)&u[nm + 8 * i][64 + fb * 4];
#pragma unroll
        for (int j = 0; j < 4; ++j)
          acc[i][j] += uv.x * w[j].x + uv.y * w[j].y + uv.z * w[j].z + uv.w * w[j].w;
      }
    }
#pragma unroll
    for (int j = 0; j < 4; ++j) {
      int h = hbase + j;
      float bnv = bn[h], bcv = bc[h];
#pragma unroll
      for (int i = 0; i < 8; ++i) {
        int b = nm + 8 * i;
        tl[b][h] = acc[i][j] + bnv + ap[b] * bcv;
      }
    }
  }
  __syncthreads();

  // ---- upd-GEMM: acc[8 nodes][2 o], K=128
  {
    float acc[8][2];
#pragma unroll
    for (int i = 0; i < 8; ++i) { acc[i][0] = 0.f; acc[i][1] = 0.f; }
    const float4* Wu4 = (const float4*)Wu;
    int obase = wv * 16 + nh * 2;
#pragma unroll 4
    for (int fb = 0; fb < 32; ++fb) {
      float4 w[2];
#pragma unroll
      for (int j = 0; j < 2; ++j) w[j] = Wu4[(size_t)(obase + j) * 32 + fb];
#pragma unroll
      for (int i = 0; i < 8; ++i) {
        float4 tv = *(const float4*)&tl[nm + 8 * i][fb * 4];
#pragma unroll
        for (int j = 0; j < 2; ++j)
          acc[i][j] += tv.x * w[j].x + tv.y * w[j].y + tv.z * w[j].z + tv.w * w[j].w;
      }
    }
    float* updl = &u[0][0];  // reuse u as [64][68] upd tile
#pragma unroll
    for (int j = 0; j < 2; ++j) {
      int o = obase + j;
      float buv = bu[o];
#pragma unroll
      for (int i = 0; i < 8; ++i) {
        int b = nm + 8 * i;
        updl[b * 68 + o] = acc[i][j] + buv;
      }
    }
  }
  __syncthreads();

  // coalesced store of upd tile
  const float* updl = &u[0][0];
  for (int q = tid; q < 64 * 64; q += 256) {
    int b = q >> 6, o = q & 63;
    int n = n0 + b;
    if (n < NN) upd[(size_t)n * 64 + o] = updl[b * 68 + o];
  }
}

// ---------------- k4: KAN head. v[b][i*6+c] = {silu(upd), bases[0..4]}; out = v @ Wk^T, where(deg>0, ., x)
__global__ __launch_bounds__(256) void k4_kan(
    const float* __restrict__ upd, const float* __restrict__ Wk,
    const float* __restrict__ degw, const float* __restrict__ xin,
    const float* __restrict__ gridp, float* __restrict__ out) {
  __shared__ __align__(16) float v[32][388];
  __shared__ float degl[32];
  int tid = threadIdx.x;
  int n0 = blockIdx.x * 32;

  float g[8];
#pragma unroll
  for (int j = 0; j < 8; ++j) g[j] = gridp[j];  // all grid rows identical; use row 0
  float r1[7], r2[6];
#pragma unroll
  for (int j = 0; j < 7; ++j) r1[j] = 1.f / (g[j + 1] - g[j]);
#pragma unroll
  for (int j = 0; j < 6; ++j) r2[j] = 1.f / (g[j + 2] - g[j]);

  // stage + nonlinear transform
  for (int q = tid; q < 32 * 64; q += 256) {
    int b = q >> 6, i = q & 63;
    int n = n0 + b;
    float xv = (n < NN) ? upd[(size_t)n * 64 + i] : 0.f;
    float sil = xv / (1.f + __expf(-xv));
    float b0[7], b1[6], b2[5];
#pragma unroll
    for (int j = 0; j < 7; ++j) b0[j] = (xv >= g[j] && xv < g[j + 1]) ? 1.f : 0.f;
#pragma unroll
    for (int j = 0; j < 6; ++j)
      b1[j] = (xv - g[j]) * r1[j] * b0[j] + (g[j + 2] - xv) * r1[j + 1] * b0[j + 1];
#pragma unroll
    for (int j = 0; j < 5; ++j)
      b2[j] = (xv - g[j]) * r2[j] * b1[j] + (g[j + 3] - xv) * r2[j + 1] * b1[j + 1];
    float* dst = &v[b][i * 6];
    dst[0] = sil;
#pragma unroll
    for (int k = 0; k < 5; ++k) dst[1 + k] = b2[k];
  }
  if (tid < 32) {
    int n = n0 + tid;
    degl[tid] = (n < NN) ? degw[n] : 1.f;
  }
  __syncthreads();

  int wv = tid >> 6, lane = tid & 63;
  int nm = lane & 7, nh = lane >> 3;
  int obase = wv * 16 + nh * 2;
  float acc[4][2];
#pragma unroll
  for (int i = 0; i < 4; ++i) { acc[i][0] = 0.f; acc[i][1] = 0.f; }
  const float4* Wk4 = (const float4*)Wk;
#pragma unroll 4
  for (int kb = 0; kb < 96; ++kb) {  // K = 384
    float4 w[2];
#pragma unroll
    for (int j = 0; j < 2; ++j) w[j] = Wk4[(size_t)(obase + j) * 96 + kb];
#pragma unroll
    for (int i = 0; i < 4; ++i) {
      float4 vv = *(const float4*)&v[nm + 8 * i][kb * 4];
#pragma unroll
      for (int j = 0; j < 2; ++j)
        acc[i][j] += vv.x * w[j].x + vv.y * w[j].y + vv.z * w[j].z + vv.w * w[j].w;
    }
  }
  __syncthreads();  // everyone done reading v; reuse as out tile [32][68]

  float* ot = &v[0][0];
#pragma unroll
  for (int j = 0; j < 2; ++j) {
#pragma unroll
    for (int i = 0; i < 4; ++i) {
      int b = nm + 8 * i, o = obase + j;
      float val = acc[i][j];
      if (degl[b] <= 0.f) {
        int n = n0 + b;
        if (n < NN) val = xin[(size_t)n * 64 + o];
      }
      ot[b * 68 + o] = val;
    }
  }
  __syncthreads();
  for (int q = tid; q < 32 * 64; q += 256) {
    int b = q >> 6, o = q & 63;
    int n = n0 + b;
    if (n < NN) out[(size_t)n * 64 + o] = ot[b * 68 + o];
  }
}

extern "C" void kernel_launch(void* const* d_in, const int* in_sizes, int n_in,
                              void* d_out, int out_size, void* d_ws, size_t ws_size,
                              hipStream_t stream) {
  const float* x        = (const float*)d_in[0];
  const float* contexts = (const float*)d_in[1];
  const float* attn     = (const float*)d_in[2];
  const int*   seg      = (const int*)d_in[3];
  const float* Wn       = (const float*)d_in[4];
  const float* bn       = (const float*)d_in[5];
  const float* Wc       = (const float*)d_in[6];
  const float* bc       = (const float*)d_in[7];
  const float* Wu       = (const float*)d_in[8];
  const float* bu       = (const float*)d_in[9];
  const float* base_w   = (const float*)d_in[10];
  const float* spline_w = (const float*)d_in[11];
  const float* scaler   = (const float*)d_in[12];
  const float* gridp    = (const float*)d_in[13];
  float* out = (float*)d_out;

  float* ws     = (float*)d_ws;
  float* Sp     = ws;                  // N*64
  float* aprime = Sp + 3200000;        // N
  float* degw   = aprime + 50000;      // N
  float* upd    = degw + 50000;        // N*64
  float* Wk     = upd + 3200000;       // 64*384 = 24576
  int*   off    = (int*)(Wk + 24576);  // N+1

  k0_pack<<<16, 256, 0, stream>>>(base_w, spline_w, scaler, Wk);
  k_off<<<3125, 256, 0, stream>>>(seg, off);
  k1_edge_agg<<<3125, 1024, 0, stream>>>(contexts, attn, off, Sp, aprime, degw);
  k23_gemm<<<782, 256, 0, stream>>>(x, Sp, aprime, Wn, bn, Wc, bc, Wu, bu, upd);
  k4_kan<<<1563, 256, 0, stream>>>(upd, Wk, degw, x, gridp, out);
}

// Round 5
// 97.691 us; speedup vs baseline: 1.8224x; 1.7931x over previous
//
#include <hip/hip_runtime.h>
#include <hip/hip_bf16.h>

#define NN 50000
#define NE 800000

typedef short short8 __attribute__((ext_vector_type(8)));
typedef float f32x4 __attribute__((ext_vector_type(4)));
typedef unsigned short ushort_t;

static __device__ __forceinline__ ushort_t f2bf(float f) {
  unsigned u = __float_as_uint(f);
  unsigned r = (u + 0x7FFF + ((u >> 16) & 1)) >> 16;
  return (ushort_t)r;
}
static __device__ __forceinline__ float bf2f(ushort_t b) {
  return __uint_as_float(((unsigned)b) << 16);
}

#define MFMA(a, b, c) __builtin_amdgcn_mfma_f32_16x16x32_bf16(a, b, c, 0, 0, 0)

// ---------------- k0: pack all weights into MFMA B-fragment lane order, bf16 hi/lo.
// B-frag for W[N][K]: P[((nt*KS+ks)*64+l)*8+j] = W[nt*16+(l&15)][ks*32+8*(l>>4)+j]
// P1: Wnc[h=128][f=128] (f<64: Wn, f>=64: Wc), 8 nt x 4 ks -> 2048 entries
// P2: Wu[o=64][h=128], 4 nt x 4 ks -> 1024 entries
// P3: Wk2[o=64][K=384], K=i*6+c: c==0 -> base_w[o][i], else spline_w[o][i][c-1]*scaler[o][i]; 4 nt x 12 ks -> 3072
__global__ __launch_bounds__(256) void k0_pack(
    const float* __restrict__ Wn, const float* __restrict__ Wc,
    const float* __restrict__ Wu, const float* __restrict__ base_w,
    const float* __restrict__ spline_w, const float* __restrict__ scaler,
    ushort_t* __restrict__ p1h, ushort_t* __restrict__ p1l,
    ushort_t* __restrict__ p2h, ushort_t* __restrict__ p2l,
    ushort_t* __restrict__ p3h, ushort_t* __restrict__ p3l) {
  int t = blockIdx.x * 256 + threadIdx.x;  // 0..4095
  int l = t & 63, lm = l & 15, lk = l >> 4;
  if (t < 2048) {
    int nt = t >> 8, ks = (t >> 6) & 3;
    int h = nt * 16 + lm;
#pragma unroll
    for (int j = 0; j < 8; ++j) {
      int f = ks * 32 + lk * 8 + j;
      float v = (f < 64) ? Wn[h * 64 + f] : Wc[h * 64 + (f - 64)];
      ushort_t hi = f2bf(v);
      p1h[t * 8 + j] = hi;
      p1l[t * 8 + j] = f2bf(v - bf2f(hi));
    }
  }
  if (t < 1024) {
    int nt = t >> 8, ks = (t >> 6) & 3;
    int o = nt * 16 + lm;
#pragma unroll
    for (int j = 0; j < 8; ++j) {
      int hh = ks * 32 + lk * 8 + j;
      float v = Wu[o * 128 + hh];
      ushort_t hi = f2bf(v);
      p2h[t * 8 + j] = hi;
      p2l[t * 8 + j] = f2bf(v - bf2f(hi));
    }
  }
  if (t < 3072) {
    int nt = t / 768, ks = (t >> 6) % 12;
    int o = nt * 16 + lm;
#pragma unroll
    for (int j = 0; j < 8; ++j) {
      int k = ks * 32 + lk * 8 + j;
      int i = k / 6, c = k % 6;
      float v = (c == 0) ? base_w[o * 64 + i]
                         : spline_w[(o * 64 + i) * 5 + (c - 1)] * scaler[o * 64 + i];
      ushort_t hi = f2bf(v);
      p3h[t * 8 + j] = hi;
      p3l[t * 8 + j] = f2bf(v - bf2f(hi));
    }
  }
}

// ---------------- k_off: CSR offsets from sorted seg_ids.
__global__ __launch_bounds__(256) void k_off(const int* __restrict__ seg, int* __restrict__ off) {
  int e = blockIdx.x * 256 + threadIdx.x;
  if (e >= NE) return;
  int s1 = seg[e];
  if (e == 0) {
    for (int n = 0; n <= s1; ++n) off[n] = 0;
  } else {
    int s0 = seg[e - 1];
    for (int n = s0 + 1; n <= s1; ++n) off[n] = e;
  }
  if (e == NE - 1) {
    for (int n = s1 + 1; n <= NN; ++n) off[n] = NE;
  }
}

// ---------------- k1: per-node edge aggregation. One wave per node, 16 edges per iteration.
__global__ __launch_bounds__(1024) void k1_edge_agg(
    const float* __restrict__ contexts, const float* __restrict__ attn,
    const int* __restrict__ off, float* __restrict__ Sp,
    float* __restrict__ aprime, float* __restrict__ degw) {
  int n = blockIdx.x * 16 + (threadIdx.x >> 6);
  int lane = threadIdx.x & 63;
  if (n >= NN) return;
  int s = off[n];
  int e_end = off[n + 1];
  int deg_i = e_end - s;

  int sub = lane >> 4;
  int fq = lane & 15;
  const float4* ctx4 = (const float4*)contexts;

  float4 S = make_float4(0.f, 0.f, 0.f, 0.f);
  float A = 0.f;
  if (deg_i > 0) {
    int last = e_end - 1;
    for (int e0 = s; e0 < e_end; e0 += 16) {
      float a[4];
      float4 c[4];
#pragma unroll
      for (int u = 0; u < 4; ++u) {
        int eu = e0 + 4 * u + sub;
        a[u] = (eu < e_end) ? attn[eu] : 0.f;
        c[u] = ctx4[(size_t)min(eu, last) * 16 + fq];
      }
#pragma unroll
      for (int u = 0; u < 4; ++u) {
        S.x += a[u] * c[u].x;
        S.y += a[u] * c[u].y;
        S.z += a[u] * c[u].z;
        S.w += a[u] * c[u].w;
        A += a[u];
      }
    }
  }
#pragma unroll
  for (int m = 16; m <= 32; m <<= 1) {
    S.x += __shfl_xor(S.x, m);
    S.y += __shfl_xor(S.y, m);
    S.z += __shfl_xor(S.z, m);
    S.w += __shfl_xor(S.w, m);
    A += __shfl_xor(A, m);
  }
  float deg = (float)deg_i;
  float inv = 1.f / fmaxf(deg, 1.f);
  if (lane < 16) {
    float4 o = make_float4(S.x * inv, S.y * inv, S.z * inv, S.w * inv);
    ((float4*)Sp)[(size_t)n * 16 + lane] = o;
  }
  if (lane == 0) { aprime[n] = A * inv; degw[n] = deg; }
}

// ---------------- k23_mfma: t = [x|Sp]@Wnc^T + bn + a'*bc ; upd = t@Wu^T + bu
// 64-node tile, 256 threads (4 waves). Wave w owns node stripe w*16..w*16+15.
// LDS: U (hi/lo) [64][136] bf16, overlaid by T after GEMM1.
__global__ __launch_bounds__(256) void k23_mfma(
    const float* __restrict__ x, const float* __restrict__ Sp,
    const float* __restrict__ aprime,
    const float* __restrict__ bn, const float* __restrict__ bc,
    const float* __restrict__ bu,
    const ushort_t* __restrict__ p1h, const ushort_t* __restrict__ p1l,
    const ushort_t* __restrict__ p2h, const ushort_t* __restrict__ p2l,
    float* __restrict__ upd) {
  __shared__ __align__(16) ushort_t Uh[64 * 136];
  __shared__ __align__(16) ushort_t Ul[64 * 136];
  __shared__ float ap[64];
  int tid = threadIdx.x;
  int n0 = blockIdx.x * 64;

  // stage [x|Sp] as bf16 hi/lo
  for (int q = tid; q < 64 * 32; q += 256) {
    int b = q >> 5, c = q & 31;
    int n = n0 + b;
    float4 val = make_float4(0.f, 0.f, 0.f, 0.f);
    if (n < NN) {
      if (c < 16) val = *(const float4*)(x + (size_t)n * 64 + c * 4);
      else        val = *(const float4*)(Sp + (size_t)n * 64 + (c - 16) * 4);
    }
    ushort_t h0 = f2bf(val.x), h1 = f2bf(val.y), h2 = f2bf(val.z), h3 = f2bf(val.w);
    ushort_t l0 = f2bf(val.x - bf2f(h0)), l1 = f2bf(val.y - bf2f(h1));
    ushort_t l2 = f2bf(val.z - bf2f(h2)), l3 = f2bf(val.w - bf2f(h3));
    uint2 hp, lp;
    hp.x = (unsigned)h0 | ((unsigned)h1 << 16);
    hp.y = (unsigned)h2 | ((unsigned)h3 << 16);
    lp.x = (unsigned)l0 | ((unsigned)l1 << 16);
    lp.y = (unsigned)l2 | ((unsigned)l3 << 16);
    *(uint2*)&Uh[b * 136 + c * 4] = hp;
    *(uint2*)&Ul[b * 136 + c * 4] = lp;
  }
  if (tid < 64) {
    int n = n0 + tid;
    ap[tid] = (n < NN) ? aprime[n] : 0.f;
  }
  __syncthreads();

  int w = tid >> 6, l = tid & 63;
  int lm = l & 15, lk = l >> 4;
  const short8* P1h = (const short8*)p1h;
  const short8* P1l = (const short8*)p1l;
  const short8* P2h = (const short8*)p2h;
  const short8* P2l = (const short8*)p2l;

  // ---- GEMM1: t[64][128], K=128. acc[ht] covers h-tile ht.
  f32x4 acc[8];
#pragma unroll
  for (int ht = 0; ht < 8; ++ht) acc[ht] = (f32x4){0.f, 0.f, 0.f, 0.f};
#pragma unroll
  for (int ks = 0; ks < 4; ++ks) {
    short8 ah = *(const short8*)&Uh[(w * 16 + lm) * 136 + ks * 32 + lk * 8];
    short8 al = *(const short8*)&Ul[(w * 16 + lm) * 136 + ks * 32 + lk * 8];
#pragma unroll
    for (int ht = 0; ht < 8; ++ht) {
      short8 bh = P1h[(ht * 4 + ks) * 64 + l];
      short8 bl = P1l[(ht * 4 + ks) * 64 + l];
      acc[ht] = MFMA(ah, bh, acc[ht]);
      acc[ht] = MFMA(al, bh, acc[ht]);
      acc[ht] = MFMA(ah, bl, acc[ht]);
    }
  }
  __syncthreads();  // all GEMM1 LDS reads done; overlay T onto U

  // bias + write T (bf16 hi/lo) : thread holds t[node=w*16+lk*4+r][h=ht*16+lm]
#pragma unroll
  for (int ht = 0; ht < 8; ++ht) {
    int h = ht * 16 + lm;
    float bnv = bn[h], bcv = bc[h];
#pragma unroll
    for (int r = 0; r < 4; ++r) {
      int node = w * 16 + lk * 4 + r;
      float t = acc[ht][r] + bnv + ap[node] * bcv;
      ushort_t th = f2bf(t);
      Uh[node * 136 + h] = th;
      Ul[node * 136 + h] = f2bf(t - bf2f(th));
    }
  }
  __syncthreads();

  // ---- GEMM2: upd[64][64], K=128
  f32x4 acc2[4];
#pragma unroll
  for (int nt = 0; nt < 4; ++nt) acc2[nt] = (f32x4){0.f, 0.f, 0.f, 0.f};
#pragma unroll
  for (int ks = 0; ks < 4; ++ks) {
    short8 ah = *(const short8*)&Uh[(w * 16 + lm) * 136 + ks * 32 + lk * 8];
    short8 al = *(const short8*)&Ul[(w * 16 + lm) * 136 + ks * 32 + lk * 8];
#pragma unroll
    for (int nt = 0; nt < 4; ++nt) {
      short8 bh = P2h[(nt * 4 + ks) * 64 + l];
      short8 bl = P2l[(nt * 4 + ks) * 64 + l];
      acc2[nt] = MFMA(ah, bh, acc2[nt]);
      acc2[nt] = MFMA(al, bh, acc2[nt]);
      acc2[nt] = MFMA(ah, bl, acc2[nt]);
    }
  }
  // store upd
#pragma unroll
  for (int nt = 0; nt < 4; ++nt) {
    int o = nt * 16 + lm;
    float buv = bu[o];
#pragma unroll
    for (int r = 0; r < 4; ++r) {
      int node = w * 16 + lk * 4 + r;
      int n = n0 + node;
      if (n < NN) upd[(size_t)n * 64 + o] = acc2[nt][r] + buv;
    }
  }
}

// ---------------- k4_mfma: KAN head. v = {silu(upd), bases}, out = v @ Wk2^T, deg fallback.
// 32-node tile, 256 threads (4 waves). M-tiles 2, N-tiles 4, K=384 (12 ks).
__global__ __launch_bounds__(256) void k4_mfma(
    const float* __restrict__ upd,
    const ushort_t* __restrict__ p3h, const ushort_t* __restrict__ p3l,
    const float* __restrict__ degw, const float* __restrict__ xin,
    const float* __restrict__ gridp, float* __restrict__ out) {
  __shared__ __align__(16) ushort_t Vh[32 * 392];
  __shared__ __align__(16) ushort_t Vl[32 * 392];
  __shared__ float degl[32];
  int tid = threadIdx.x;
  int n0 = blockIdx.x * 32;

  float g[8];
#pragma unroll
  for (int j = 0; j < 8; ++j) g[j] = gridp[j];
  float r1[7], r2[6];
#pragma unroll
  for (int j = 0; j < 7; ++j) r1[j] = 1.f / (g[j + 1] - g[j]);
#pragma unroll
  for (int j = 0; j < 6; ++j) r2[j] = 1.f / (g[j + 2] - g[j]);

  // transform: thread handles node=tid>>3, inputs i0..i0+7
  {
    int node = tid >> 3;
    int i0 = (tid & 7) * 8;
    int n = n0 + node;
    float uv[8];
    if (n < NN) {
      float4 a = *(const float4*)(upd + (size_t)n * 64 + i0);
      float4 b = *(const float4*)(upd + (size_t)n * 64 + i0 + 4);
      uv[0] = a.x; uv[1] = a.y; uv[2] = a.z; uv[3] = a.w;
      uv[4] = b.x; uv[5] = b.y; uv[6] = b.z; uv[7] = b.w;
    } else {
#pragma unroll
      for (int j = 0; j < 8; ++j) uv[j] = 0.f;
    }
#pragma unroll
    for (int j = 0; j < 8; ++j) {
      float xv = uv[j];
      float sil = xv / (1.f + __expf(-xv));
      float b0[7], b1[6], b2[5];
#pragma unroll
      for (int q = 0; q < 7; ++q) b0[q] = (xv >= g[q] && xv < g[q + 1]) ? 1.f : 0.f;
#pragma unroll
      for (int q = 0; q < 6; ++q)
        b1[q] = (xv - g[q]) * r1[q] * b0[q] + (g[q + 2] - xv) * r1[q + 1] * b0[q + 1];
#pragma unroll
      for (int q = 0; q < 5; ++q)
        b2[q] = (xv - g[q]) * r2[q] * b1[q] + (g[q + 3] - xv) * r2[q + 1] * b1[q + 1];
      ushort_t h0 = f2bf(sil), h1 = f2bf(b2[0]), h2 = f2bf(b2[1]);
      ushort_t h3 = f2bf(b2[2]), h4 = f2bf(b2[3]), h5 = f2bf(b2[4]);
      ushort_t q0 = f2bf(sil - bf2f(h0)), q1 = f2bf(b2[0] - bf2f(h1)), q2 = f2bf(b2[1] - bf2f(h2));
      ushort_t q3 = f2bf(b2[2] - bf2f(h3)), q4 = f2bf(b2[3] - bf2f(h4)), q5 = f2bf(b2[4] - bf2f(h5));
      int base = node * 392 + (i0 + j) * 6;  // ushort index, byte = *2 (4-aligned since 12|bytes)
      *(unsigned*)&Vh[base + 0] = (unsigned)h0 | ((unsigned)h1 << 16);
      *(unsigned*)&Vh[base + 2] = (unsigned)h2 | ((unsigned)h3 << 16);
      *(unsigned*)&Vh[base + 4] = (unsigned)h4 | ((unsigned)h5 << 16);
      *(unsigned*)&Vl[base + 0] = (unsigned)q0 | ((unsigned)q1 << 16);
      *(unsigned*)&Vl[base + 2] = (unsigned)q2 | ((unsigned)q3 << 16);
      *(unsigned*)&Vl[base + 4] = (unsigned)q4 | ((unsigned)q5 << 16);
    }
  }
  if (tid < 32) {
    int n = n0 + tid;
    degl[tid] = (n < NN) ? degw[n] : 1.f;
  }
  __syncthreads();

  int w = tid >> 6, l = tid & 63;
  int lm = l & 15, lk = l >> 4;
  int mt = w & 1;        // node half
  int np = w >> 1;       // n-tile pair
  const short8* P3h = (const short8*)p3h;
  const short8* P3l = (const short8*)p3l;

  f32x4 acc[2];
  acc[0] = (f32x4){0.f, 0.f, 0.f, 0.f};
  acc[1] = (f32x4){0.f, 0.f, 0.f, 0.f};
#pragma unroll
  for (int ks = 0; ks < 12; ++ks) {
    short8 ah = *(const short8*)&Vh[(mt * 16 + lm) * 392 + ks * 32 + lk * 8];
    short8 al = *(const short8*)&Vl[(mt * 16 + lm) * 392 + ks * 32 + lk * 8];
#pragma unroll
    for (int q = 0; q < 2; ++q) {
      int nt = np * 2 + q;
      short8 bh = P3h[(nt * 12 + ks) * 64 + l];
      short8 bl = P3l[(nt * 12 + ks) * 64 + l];
      acc[q] = MFMA(ah, bh, acc[q]);
      acc[q] = MFMA(al, bh, acc[q]);
      acc[q] = MFMA(ah, bl, acc[q]);
    }
  }

  // epilogue: deg fallback + store. node = mt*16 + lk*4 + r, o = nt*16 + lm
#pragma unroll
  for (int q = 0; q < 2; ++q) {
    int o = (np * 2 + q) * 16 + lm;
#pragma unroll
    for (int r = 0; r < 4; ++r) {
      int node = mt * 16 + lk * 4 + r;
      int n = n0 + node;
      if (n < NN) {
        float val = acc[q][r];
        if (degl[node] <= 0.f) val = xin[(size_t)n * 64 + o];
        out[(size_t)n * 64 + o] = val;
      }
    }
  }
}

extern "C" void kernel_launch(void* const* d_in, const int* in_sizes, int n_in,
                              void* d_out, int out_size, void* d_ws, size_t ws_size,
                              hipStream_t stream) {
  const float* x        = (const float*)d_in[0];
  const float* contexts = (const float*)d_in[1];
  const float* attn     = (const float*)d_in[2];
  const int*   seg      = (const int*)d_in[3];
  const float* Wn       = (const float*)d_in[4];
  const float* bn       = (const float*)d_in[5];
  const float* Wc       = (const float*)d_in[6];
  const float* bc       = (const float*)d_in[7];
  const float* Wu       = (const float*)d_in[8];
  const float* bu       = (const float*)d_in[9];
  const float* base_w   = (const float*)d_in[10];
  const float* spline_w = (const float*)d_in[11];
  const float* scaler   = (const float*)d_in[12];
  const float* gridp    = (const float*)d_in[13];
  float* out = (float*)d_out;

  float* ws     = (float*)d_ws;
  float* Sp     = ws;                    // 3,200,000
  float* aprime = Sp + 3200000;          // 50,000
  float* degw   = aprime + 50000;        // 50,000
  float* upd    = degw + 50000;          // 3,200,000
  ushort_t* p1h = (ushort_t*)(upd + 3200000);  // 16384
  ushort_t* p1l = p1h + 16384;
  ushort_t* p2h = p1l + 16384;           // 8192
  ushort_t* p2l = p2h + 8192;
  ushort_t* p3h = p2l + 8192;            // 24576
  ushort_t* p3l = p3h + 24576;
  int* off      = (int*)(p3l + 24576);   // 50,001

  k0_pack<<<16, 256, 0, stream>>>(Wn, Wc, Wu, base_w, spline_w, scaler,
                                  p1h, p1l, p2h, p2l, p3h, p3l);
  k_off<<<3125, 256, 0, stream>>>(seg, off);
  k1_edge_agg<<<3125, 1024, 0, stream>>>(contexts, attn, off, Sp, aprime, degw);
  k23_mfma<<<782, 256, 0, stream>>>(x, Sp, aprime, bn, bc, bu,
                                    p1h, p1l, p2h, p2l, upd);
  k4_mfma<<<1563, 256, 0, stream>>>(upd, p3h, p3l, degw, x, gridp, out);
}

// Round 6
// 91.018 us; speedup vs baseline: 1.9560x; 1.0733x over previous
//
#include <hip/hip_runtime.h>
#include <hip/hip_bf16.h>

#define NN 50000
#define NE 800000

typedef short short8 __attribute__((ext_vector_type(8)));
typedef float f32x4 __attribute__((ext_vector_type(4)));
typedef unsigned short ushort_t;

// ---- truncation-based bf16 hi/lo split helpers (cheap: and/sub/shift) ----
static __device__ __forceinline__ unsigned bits(float f) { return __float_as_uint(f); }
static __device__ __forceinline__ float hi_f(float v) {  // bf16-truncated value as f32
  return __uint_as_float(bits(v) & 0xFFFF0000u);
}
static __device__ __forceinline__ ushort_t hi_u(float v) { return (ushort_t)(bits(v) >> 16); }
static __device__ __forceinline__ ushort_t lo_u(float v) {  // truncated remainder
  return (ushort_t)(bits(v - hi_f(v)) >> 16);
}
// pack two elements' hi (or lo) into one uint: low half = e0, high half = e1
static __device__ __forceinline__ unsigned pack_hi(float v0, float v1) {
  return (bits(v0) >> 16) | (bits(v1) & 0xFFFF0000u);
}
static __device__ __forceinline__ unsigned pack_lo(float v0, float v1) {
  float l0 = v0 - hi_f(v0), l1 = v1 - hi_f(v1);
  return (bits(l0) >> 16) | (bits(l1) & 0xFFFF0000u);
}

#define MFMA(a, b, c) __builtin_amdgcn_mfma_f32_16x16x32_bf16(a, b, c, 0, 0, 0)

// ---------------- kA: merged weight-pack (blocks 0..15) + CSR offsets (all blocks).
// B-frag for W[N][K]: P[((nt*KS+ks)*64+l)*8+j] = W[nt*16+(l&15)][ks*32+8*(l>>4)+j]
__global__ __launch_bounds__(256) void kA_pack_off(
    const float* __restrict__ Wn, const float* __restrict__ Wc,
    const float* __restrict__ Wu, const float* __restrict__ base_w,
    const float* __restrict__ spline_w, const float* __restrict__ scaler,
    const int* __restrict__ seg,
    ushort_t* __restrict__ p1h, ushort_t* __restrict__ p1l,
    ushort_t* __restrict__ p2h, ushort_t* __restrict__ p2l,
    ushort_t* __restrict__ p3h, ushort_t* __restrict__ p3l,
    int* __restrict__ off) {
  int t = blockIdx.x * 256 + threadIdx.x;
  // ---- pack part (t < 4096)
  if (t < 4096) {
    int l = t & 63, lm = l & 15, lk = l >> 4;
    if (t < 2048) {
      int nt = t >> 8, ks = (t >> 6) & 3;
      int h = nt * 16 + lm;
#pragma unroll
      for (int j = 0; j < 8; ++j) {
        int f = ks * 32 + lk * 8 + j;
        float v = (f < 64) ? Wn[h * 64 + f] : Wc[h * 64 + (f - 64)];
        p1h[t * 8 + j] = hi_u(v);
        p1l[t * 8 + j] = lo_u(v);
      }
    }
    if (t < 1024) {
      int nt = t >> 8, ks = (t >> 6) & 3;
      int o = nt * 16 + lm;
#pragma unroll
      for (int j = 0; j < 8; ++j) {
        int hh = ks * 32 + lk * 8 + j;
        float v = Wu[o * 128 + hh];
        p2h[t * 8 + j] = hi_u(v);
        p2l[t * 8 + j] = lo_u(v);
      }
    }
    if (t < 3072) {
      int nt = t / 768, ks = (t >> 6) % 12;
      int o = nt * 16 + lm;
#pragma unroll
      for (int j = 0; j < 8; ++j) {
        int k = ks * 32 + lk * 8 + j;
        int i = k / 6, c = k % 6;
        float v = (c == 0) ? base_w[o * 64 + i]
                           : spline_w[(o * 64 + i) * 5 + (c - 1)] * scaler[o * 64 + i];
        p3h[t * 8 + j] = hi_u(v);
        p3l[t * 8 + j] = lo_u(v);
      }
    }
  }
  // ---- off part
  int e = t;
  if (e < NE) {
    int s1 = seg[e];
    if (e == 0) {
      for (int n = 0; n <= s1; ++n) off[n] = 0;
    } else {
      int s0 = seg[e - 1];
      for (int n = s0 + 1; n <= s1; ++n) off[n] = e;
    }
    if (e == NE - 1) {
      for (int n = s1 + 1; n <= NN; ++n) off[n] = NE;
    }
  }
}

// ---------------- k1: per-node edge aggregation. One wave per node, 16 edges per iteration.
__global__ __launch_bounds__(256) void k1_edge_agg(
    const float* __restrict__ contexts, const float* __restrict__ attn,
    const int* __restrict__ off, float* __restrict__ Sp,
    float* __restrict__ aprime, float* __restrict__ degw) {
  int n = blockIdx.x * 4 + (threadIdx.x >> 6);
  int lane = threadIdx.x & 63;
  if (n >= NN) return;
  int s = off[n];
  int e_end = off[n + 1];
  int deg_i = e_end - s;

  int sub = lane >> 4;
  int fq = lane & 15;
  const float4* ctx4 = (const float4*)contexts;

  float4 S = make_float4(0.f, 0.f, 0.f, 0.f);
  float A = 0.f;
  if (deg_i > 0) {
    int last = e_end - 1;
    for (int e0 = s; e0 < e_end; e0 += 16) {
      float a[4];
      float4 c[4];
#pragma unroll
      for (int u = 0; u < 4; ++u) {
        int eu = e0 + 4 * u + sub;
        a[u] = (eu < e_end) ? attn[eu] : 0.f;
        c[u] = ctx4[(size_t)min(eu, last) * 16 + fq];
      }
#pragma unroll
      for (int u = 0; u < 4; ++u) {
        S.x += a[u] * c[u].x;
        S.y += a[u] * c[u].y;
        S.z += a[u] * c[u].z;
        S.w += a[u] * c[u].w;
        A += a[u];
      }
    }
  }
#pragma unroll
  for (int m = 16; m <= 32; m <<= 1) {
    S.x += __shfl_xor(S.x, m);
    S.y += __shfl_xor(S.y, m);
    S.z += __shfl_xor(S.z, m);
    S.w += __shfl_xor(S.w, m);
    A += __shfl_xor(A, m);
  }
  float deg = (float)deg_i;
  float inv = 1.f / fmaxf(deg, 1.f);
  if (lane < 16) {
    float4 o = make_float4(S.x * inv, S.y * inv, S.z * inv, S.w * inv);
    ((float4*)Sp)[(size_t)n * 16 + lane] = o;
  }
  if (lane == 0) { aprime[n] = A * inv; degw[n] = deg; }
}

// ---------------- k23_mfma: t = [x|Sp]@Wnc^T + bn + a'*bc ; upd = t@Wu^T + bu
__global__ __launch_bounds__(256) void k23_mfma(
    const float* __restrict__ x, const float* __restrict__ Sp,
    const float* __restrict__ aprime,
    const float* __restrict__ bn, const float* __restrict__ bc,
    const float* __restrict__ bu,
    const ushort_t* __restrict__ p1h, const ushort_t* __restrict__ p1l,
    const ushort_t* __restrict__ p2h, const ushort_t* __restrict__ p2l,
    float* __restrict__ upd) {
  __shared__ __align__(16) ushort_t Uh[64 * 136];
  __shared__ __align__(16) ushort_t Ul[64 * 136];
  __shared__ float ap[64];
  int tid = threadIdx.x;
  int n0 = blockIdx.x * 64;

  // stage [x|Sp] as bf16 hi/lo (truncation split)
  for (int q = tid; q < 64 * 32; q += 256) {
    int b = q >> 5, c = q & 31;
    int n = n0 + b;
    float4 val = make_float4(0.f, 0.f, 0.f, 0.f);
    if (n < NN) {
      if (c < 16) val = *(const float4*)(x + (size_t)n * 64 + c * 4);
      else        val = *(const float4*)(Sp + (size_t)n * 64 + (c - 16) * 4);
    }
    uint2 hp, lp;
    hp.x = pack_hi(val.x, val.y);
    hp.y = pack_hi(val.z, val.w);
    lp.x = pack_lo(val.x, val.y);
    lp.y = pack_lo(val.z, val.w);
    *(uint2*)&Uh[b * 136 + c * 4] = hp;
    *(uint2*)&Ul[b * 136 + c * 4] = lp;
  }
  if (tid < 64) {
    int n = n0 + tid;
    ap[tid] = (n < NN) ? aprime[n] : 0.f;
  }
  __syncthreads();

  int w = tid >> 6, l = tid & 63;
  int lm = l & 15, lk = l >> 4;
  const short8* P1h = (const short8*)p1h;
  const short8* P1l = (const short8*)p1l;
  const short8* P2h = (const short8*)p2h;
  const short8* P2l = (const short8*)p2l;

  // ---- GEMM1: t[64][128], K=128
  f32x4 acc[8];
#pragma unroll
  for (int ht = 0; ht < 8; ++ht) acc[ht] = (f32x4){0.f, 0.f, 0.f, 0.f};
#pragma unroll
  for (int ks = 0; ks < 4; ++ks) {
    short8 ah = *(const short8*)&Uh[(w * 16 + lm) * 136 + ks * 32 + lk * 8];
    short8 al = *(const short8*)&Ul[(w * 16 + lm) * 136 + ks * 32 + lk * 8];
#pragma unroll
    for (int ht = 0; ht < 8; ++ht) {
      short8 bh = P1h[(ht * 4 + ks) * 64 + l];
      short8 bl = P1l[(ht * 4 + ks) * 64 + l];
      acc[ht] = MFMA(ah, bh, acc[ht]);
      acc[ht] = MFMA(al, bh, acc[ht]);
      acc[ht] = MFMA(ah, bl, acc[ht]);
    }
  }
  __syncthreads();  // all GEMM1 LDS reads done; overlay T onto U

  // bias + write T (bf16 hi/lo, trunc split): t[node=w*16+lk*4+r][h=ht*16+lm]
#pragma unroll
  for (int ht = 0; ht < 8; ++ht) {
    int h = ht * 16 + lm;
    float bnv = bn[h], bcv = bc[h];
#pragma unroll
    for (int r = 0; r < 4; ++r) {
      int node = w * 16 + lk * 4 + r;
      float t = acc[ht][r] + bnv + ap[node] * bcv;
      Uh[node * 136 + h] = hi_u(t);
      Ul[node * 136 + h] = lo_u(t);
    }
  }
  __syncthreads();

  // ---- GEMM2: upd[64][64], K=128
  f32x4 acc2[4];
#pragma unroll
  for (int nt = 0; nt < 4; ++nt) acc2[nt] = (f32x4){0.f, 0.f, 0.f, 0.f};
#pragma unroll
  for (int ks = 0; ks < 4; ++ks) {
    short8 ah = *(const short8*)&Uh[(w * 16 + lm) * 136 + ks * 32 + lk * 8];
    short8 al = *(const short8*)&Ul[(w * 16 + lm) * 136 + ks * 32 + lk * 8];
#pragma unroll
    for (int nt = 0; nt < 4; ++nt) {
      short8 bh = P2h[(nt * 4 + ks) * 64 + l];
      short8 bl = P2l[(nt * 4 + ks) * 64 + l];
      acc2[nt] = MFMA(ah, bh, acc2[nt]);
      acc2[nt] = MFMA(al, bh, acc2[nt]);
      acc2[nt] = MFMA(ah, bl, acc2[nt]);
    }
  }
#pragma unroll
  for (int nt = 0; nt < 4; ++nt) {
    int o = nt * 16 + lm;
    float buv = bu[o];
#pragma unroll
    for (int r = 0; r < 4; ++r) {
      int node = w * 16 + lk * 4 + r;
      int n = n0 + node;
      if (n < NN) upd[(size_t)n * 64 + o] = acc2[nt][r] + buv;
    }
  }
}

// ---------------- k4_mfma: KAN head. v = {silu(upd), bases}, out = v @ Wk2^T, deg fallback.
__global__ __launch_bounds__(256) void k4_mfma(
    const float* __restrict__ upd,
    const ushort_t* __restrict__ p3h, const ushort_t* __restrict__ p3l,
    const float* __restrict__ degw, const float* __restrict__ xin,
    const float* __restrict__ gridp, float* __restrict__ out) {
  __shared__ __align__(16) ushort_t Vh[32 * 392];
  __shared__ __align__(16) ushort_t Vl[32 * 392];
  __shared__ float degl[32];
  int tid = threadIdx.x;
  int n0 = blockIdx.x * 32;

  float g[8];
#pragma unroll
  for (int j = 0; j < 8; ++j) g[j] = gridp[j];
  float r1[7], r2[6];
#pragma unroll
  for (int j = 0; j < 7; ++j) r1[j] = 1.f / (g[j + 1] - g[j]);
#pragma unroll
  for (int j = 0; j < 6; ++j) r2[j] = 1.f / (g[j + 2] - g[j]);

  // transform: thread handles node=tid>>3, inputs i0..i0+7
  {
    int node = tid >> 3;
    int i0 = (tid & 7) * 8;
    int n = n0 + node;
    float uv[8];
    if (n < NN) {
      float4 a = *(const float4*)(upd + (size_t)n * 64 + i0);
      float4 b = *(const float4*)(upd + (size_t)n * 64 + i0 + 4);
      uv[0] = a.x; uv[1] = a.y; uv[2] = a.z; uv[3] = a.w;
      uv[4] = b.x; uv[5] = b.y; uv[6] = b.z; uv[7] = b.w;
    } else {
#pragma unroll
      for (int j = 0; j < 8; ++j) uv[j] = 0.f;
    }
#pragma unroll
    for (int j = 0; j < 8; ++j) {
      float xv = uv[j];
      float sil = xv / (1.f + __expf(-xv));
      float b0[7], b1[6], b2[5];
#pragma unroll
      for (int q = 0; q < 7; ++q) b0[q] = (xv >= g[q] && xv < g[q + 1]) ? 1.f : 0.f;
#pragma unroll
      for (int q = 0; q < 6; ++q)
        b1[q] = (xv - g[q]) * r1[q] * b0[q] + (g[q + 2] - xv) * r1[q + 1] * b0[q + 1];
#pragma unroll
      for (int q = 0; q < 5; ++q)
        b2[q] = (xv - g[q]) * r2[q] * b1[q] + (g[q + 3] - xv) * r2[q + 1] * b1[q + 1];
      int base = node * 392 + (i0 + j) * 6;  // ushort index, uint-aligned
      *(unsigned*)&Vh[base + 0] = pack_hi(sil, b2[0]);
      *(unsigned*)&Vh[base + 2] = pack_hi(b2[1], b2[2]);
      *(unsigned*)&Vh[base + 4] = pack_hi(b2[3], b2[4]);
      *(unsigned*)&Vl[base + 0] = pack_lo(sil, b2[0]);
      *(unsigned*)&Vl[base + 2] = pack_lo(b2[1], b2[2]);
      *(unsigned*)&Vl[base + 4] = pack_lo(b2[3], b2[4]);
    }
  }
  if (tid < 32) {
    int n = n0 + tid;
    degl[tid] = (n < NN) ? degw[n] : 1.f;
  }
  __syncthreads();

  int w = tid >> 6, l = tid & 63;
  int lm = l & 15, lk = l >> 4;
  int mt = w & 1;
  int np = w >> 1;
  const short8* P3h = (const short8*)p3h;
  const short8* P3l = (const short8*)p3l;

  f32x4 acc[2];
  acc[0] = (f32x4){0.f, 0.f, 0.f, 0.f};
  acc[1] = (f32x4){0.f, 0.f, 0.f, 0.f};
#pragma unroll
  for (int ks = 0; ks < 12; ++ks) {
    short8 ah = *(const short8*)&Vh[(mt * 16 + lm) * 392 + ks * 32 + lk * 8];
    short8 al = *(const short8*)&Vl[(mt * 16 + lm) * 392 + ks * 32 + lk * 8];
#pragma unroll
    for (int q = 0; q < 2; ++q) {
      int nt = np * 2 + q;
      short8 bh = P3h[(nt * 12 + ks) * 64 + l];
      short8 bl = P3l[(nt * 12 + ks) * 64 + l];
      acc[q] = MFMA(ah, bh, acc[q]);
      acc[q] = MFMA(al, bh, acc[q]);
      acc[q] = MFMA(ah, bl, acc[q]);
    }
  }

#pragma unroll
  for (int q = 0; q < 2; ++q) {
    int o = (np * 2 + q) * 16 + lm;
#pragma unroll
    for (int r = 0; r < 4; ++r) {
      int node = mt * 16 + lk * 4 + r;
      int n = n0 + node;
      if (n < NN) {
        float val = acc[q][r];
        if (degl[node] <= 0.f) val = xin[(size_t)n * 64 + o];
        out[(size_t)n * 64 + o] = val;
      }
    }
  }
}

extern "C" void kernel_launch(void* const* d_in, const int* in_sizes, int n_in,
                              void* d_out, int out_size, void* d_ws, size_t ws_size,
                              hipStream_t stream) {
  const float* x        = (const float*)d_in[0];
  const float* contexts = (const float*)d_in[1];
  const float* attn     = (const float*)d_in[2];
  const int*   seg      = (const int*)d_in[3];
  const float* Wn       = (const float*)d_in[4];
  const float* bn       = (const float*)d_in[5];
  const float* Wc       = (const float*)d_in[6];
  const float* bc       = (const float*)d_in[7];
  const float* Wu       = (const float*)d_in[8];
  const float* bu       = (const float*)d_in[9];
  const float* base_w   = (const float*)d_in[10];
  const float* spline_w = (const float*)d_in[11];
  const float* scaler   = (const float*)d_in[12];
  const float* gridp    = (const float*)d_in[13];
  float* out = (float*)d_out;

  float* ws     = (float*)d_ws;
  float* Sp     = ws;                    // 3,200,000
  float* aprime = Sp + 3200000;          // 50,000
  float* degw   = aprime + 50000;        // 50,000
  float* upd    = degw + 50000;          // 3,200,000
  ushort_t* p1h = (ushort_t*)(upd + 3200000);  // 16384
  ushort_t* p1l = p1h + 16384;
  ushort_t* p2h = p1l + 16384;           // 8192
  ushort_t* p2l = p2h + 8192;
  ushort_t* p3h = p2l + 8192;            // 24576
  ushort_t* p3l = p3h + 24576;
  int* off      = (int*)(p3l + 24576);   // 50,001

  kA_pack_off<<<3125, 256, 0, stream>>>(Wn, Wc, Wu, base_w, spline_w, scaler, seg,
                                        p1h, p1l, p2h, p2l, p3h, p3l, off);
  k1_edge_agg<<<12500, 256, 0, stream>>>(contexts, attn, off, Sp, aprime, degw);
  k23_mfma<<<782, 256, 0, stream>>>(x, Sp, aprime, bn, bc, bu,
                                    p1h, p1l, p2h, p2l, upd);
  k4_mfma<<<1563, 256, 0, stream>>>(upd, p3h, p3l, degw, x, gridp, out);
}

// Round 7
// 88.072 us; speedup vs baseline: 2.0214x; 1.0335x over previous
//
#include <hip/hip_runtime.h>
#include <hip/hip_bf16.h>

#define NN 50000
#define NE 800000

typedef short short8 __attribute__((ext_vector_type(8)));
typedef float f32x4 __attribute__((ext_vector_type(4)));
typedef unsigned short ushort_t;

// ---- truncation-based bf16 hi/lo split helpers ----
static __device__ __forceinline__ unsigned bits(float f) { return __float_as_uint(f); }
static __device__ __forceinline__ float hi_f(float v) {
  return __uint_as_float(bits(v) & 0xFFFF0000u);
}
static __device__ __forceinline__ ushort_t hi_u(float v) { return (ushort_t)(bits(v) >> 16); }
static __device__ __forceinline__ ushort_t lo_u(float v) {
  return (ushort_t)(bits(v - hi_f(v)) >> 16);
}
static __device__ __forceinline__ unsigned pack_hi(float v0, float v1) {
  return (bits(v0) >> 16) | (bits(v1) & 0xFFFF0000u);
}
static __device__ __forceinline__ unsigned pack_lo(float v0, float v1) {
  float l0 = v0 - hi_f(v0), l1 = v1 - hi_f(v1);
  return (bits(l0) >> 16) | (bits(l1) & 0xFFFF0000u);
}

#define MFMA(a, b, c) __builtin_amdgcn_mfma_f32_16x16x32_bf16(a, b, c, 0, 0, 0)

// ---------------- kA: merged weight-pack (t < 4096) + CSR offsets (all threads).
// B-frag for W[N][K]: P[((nt*KS+ks)*64+l)*8+j] = W[nt*16+(l&15)][ks*32+8*(l>>4)+j]
__global__ __launch_bounds__(256) void kA_pack_off(
    const float* __restrict__ Wn, const float* __restrict__ Wc,
    const float* __restrict__ Wu, const float* __restrict__ base_w,
    const float* __restrict__ spline_w, const float* __restrict__ scaler,
    const int* __restrict__ seg,
    ushort_t* __restrict__ p1h, ushort_t* __restrict__ p1l,
    ushort_t* __restrict__ p2h, ushort_t* __restrict__ p2l,
    ushort_t* __restrict__ p3h, ushort_t* __restrict__ p3l,
    int* __restrict__ off) {
  int t = blockIdx.x * 256 + threadIdx.x;
  if (t < 4096) {
    int l = t & 63, lm = l & 15, lk = l >> 4;
    if (t < 2048) {
      int nt = t >> 8, ks = (t >> 6) & 3;
      int h = nt * 16 + lm;
#pragma unroll
      for (int j = 0; j < 8; ++j) {
        int f = ks * 32 + lk * 8 + j;
        float v = (f < 64) ? Wn[h * 64 + f] : Wc[h * 64 + (f - 64)];
        p1h[t * 8 + j] = hi_u(v);
        p1l[t * 8 + j] = lo_u(v);
      }
    }
    if (t < 1024) {
      int nt = t >> 8, ks = (t >> 6) & 3;
      int o = nt * 16 + lm;
#pragma unroll
      for (int j = 0; j < 8; ++j) {
        int hh = ks * 32 + lk * 8 + j;
        float v = Wu[o * 128 + hh];
        p2h[t * 8 + j] = hi_u(v);
        p2l[t * 8 + j] = lo_u(v);
      }
    }
    if (t < 3072) {
      int nt = t / 768, ks = (t >> 6) % 12;
      int o = nt * 16 + lm;
#pragma unroll
      for (int j = 0; j < 8; ++j) {
        int k = ks * 32 + lk * 8 + j;
        int i = k / 6, c = k % 6;
        float v = (c == 0) ? base_w[o * 64 + i]
                           : spline_w[(o * 64 + i) * 5 + (c - 1)] * scaler[o * 64 + i];
        p3h[t * 8 + j] = hi_u(v);
        p3l[t * 8 + j] = lo_u(v);
      }
    }
  }
  int e = t;
  if (e < NE) {
    int s1 = seg[e];
    if (e == 0) {
      for (int n = 0; n <= s1; ++n) off[n] = 0;
    } else {
      int s0 = seg[e - 1];
      for (int n = s0 + 1; n <= s1; ++n) off[n] = e;
    }
    if (e == NE - 1) {
      for (int n = s1 + 1; n <= NN; ++n) off[n] = NE;
    }
  }
}

// ---------------- k1: per-node edge aggregation. One wave per node, 16 edges per iteration.
__global__ __launch_bounds__(256) void k1_edge_agg(
    const float* __restrict__ contexts, const float* __restrict__ attn,
    const int* __restrict__ off, float* __restrict__ Sp,
    float* __restrict__ aprime, float* __restrict__ degw) {
  int n = blockIdx.x * 4 + (threadIdx.x >> 6);
  int lane = threadIdx.x & 63;
  if (n >= NN) return;
  int s = off[n];
  int e_end = off[n + 1];
  int deg_i = e_end - s;

  int sub = lane >> 4;
  int fq = lane & 15;
  const float4* ctx4 = (const float4*)contexts;

  float4 S = make_float4(0.f, 0.f, 0.f, 0.f);
  float A = 0.f;
  if (deg_i > 0) {
    int last = e_end - 1;
    for (int e0 = s; e0 < e_end; e0 += 16) {
      float a[4];
      float4 c[4];
#pragma unroll
      for (int u = 0; u < 4; ++u) {
        int eu = e0 + 4 * u + sub;
        a[u] = (eu < e_end) ? attn[eu] : 0.f;
        c[u] = ctx4[(size_t)min(eu, last) * 16 + fq];
      }
#pragma unroll
      for (int u = 0; u < 4; ++u) {
        S.x += a[u] * c[u].x;
        S.y += a[u] * c[u].y;
        S.z += a[u] * c[u].z;
        S.w += a[u] * c[u].w;
        A += a[u];
      }
    }
  }
#pragma unroll
  for (int m = 16; m <= 32; m <<= 1) {
    S.x += __shfl_xor(S.x, m);
    S.y += __shfl_xor(S.y, m);
    S.z += __shfl_xor(S.z, m);
    S.w += __shfl_xor(S.w, m);
    A += __shfl_xor(A, m);
  }
  float deg = (float)deg_i;
  float inv = 1.f / fmaxf(deg, 1.f);
  if (lane < 16) {
    float4 o = make_float4(S.x * inv, S.y * inv, S.z * inv, S.w * inv);
    ((float4*)Sp)[(size_t)n * 16 + lane] = o;
  }
  if (lane == 0) { aprime[n] = A * inv; degw[n] = deg; }
}

// ---------------- k234: fused MFMA pipeline, 64-node tile, 4 waves, N-split.
// GEMM1: t = [x|Sp]@Wnc^T + bias (wave w -> h-tiles 2w,2w+1)
// GEMM2: upd = t@Wu^T + bu     (wave w -> o-tile w), upd stays in registers
// KAN:   v = {silu,spline bases}(upd) per 32-node half -> out = v@Wk2^T (wave w -> o-tile w)
// LDS arena 50176 B: U/T hi+lo [64][136] (34816 B) overlaid by V hi+lo [32][392] (50176 B)
__global__ __launch_bounds__(256) void k234(
    const float* __restrict__ x, const float* __restrict__ Sp,
    const float* __restrict__ aprime, const float* __restrict__ degw,
    const float* __restrict__ bn, const float* __restrict__ bc,
    const float* __restrict__ bu,
    const ushort_t* __restrict__ p1h, const ushort_t* __restrict__ p1l,
    const ushort_t* __restrict__ p2h, const ushort_t* __restrict__ p2l,
    const ushort_t* __restrict__ p3h, const ushort_t* __restrict__ p3l,
    const float* __restrict__ gridp, float* __restrict__ out) {
  __shared__ __align__(16) unsigned char arena[50176];
  __shared__ float ap[64], degl[64];
  ushort_t* Uh = (ushort_t*)arena;             // [64][136]
  ushort_t* Ul = (ushort_t*)(arena + 17408);   // [64][136]
  ushort_t* Vh = (ushort_t*)arena;             // [32][392]
  ushort_t* Vl = (ushort_t*)(arena + 25088);   // [32][392]

  int tid = threadIdx.x;
  int n0 = blockIdx.x * 64;

  // spline constants (register)
  float g[8];
#pragma unroll
  for (int j = 0; j < 8; ++j) g[j] = gridp[j];
  float r1[7], r2[6];
#pragma unroll
  for (int j = 0; j < 7; ++j) r1[j] = 1.f / (g[j + 1] - g[j]);
#pragma unroll
  for (int j = 0; j < 6; ++j) r2[j] = 1.f / (g[j + 2] - g[j]);

  // ---- stage [x|Sp] as bf16 hi/lo
  for (int q = tid; q < 64 * 32; q += 256) {
    int b = q >> 5, c = q & 31;
    int n = n0 + b;
    float4 val = make_float4(0.f, 0.f, 0.f, 0.f);
    if (n < NN) {
      if (c < 16) val = *(const float4*)(x + (size_t)n * 64 + c * 4);
      else        val = *(const float4*)(Sp + (size_t)n * 64 + (c - 16) * 4);
    }
    uint2 hp, lp;
    hp.x = pack_hi(val.x, val.y);
    hp.y = pack_hi(val.z, val.w);
    lp.x = pack_lo(val.x, val.y);
    lp.y = pack_lo(val.z, val.w);
    *(uint2*)&Uh[b * 136 + c * 4] = hp;
    *(uint2*)&Ul[b * 136 + c * 4] = lp;
  }
  if (tid < 64) {
    int n = n0 + tid;
    ap[tid] = (n < NN) ? aprime[n] : 0.f;
    degl[tid] = (n < NN) ? degw[n] : 1.f;
  }
  __syncthreads();

  int w = tid >> 6, l = tid & 63;
  int lm = l & 15, lk = l >> 4;
  const short8* P1h = (const short8*)p1h;
  const short8* P1l = (const short8*)p1l;
  const short8* P2h = (const short8*)p2h;
  const short8* P2l = (const short8*)p2l;
  const short8* P3h = (const short8*)p3h;
  const short8* P3l = (const short8*)p3l;

  // ---- GEMM1 (N-split): wave w -> h-tiles {2w, 2w+1}, all 4 m-tiles. K=128.
  f32x4 acc1[4][2];
#pragma unroll
  for (int mt = 0; mt < 4; ++mt) {
    acc1[mt][0] = (f32x4){0.f, 0.f, 0.f, 0.f};
    acc1[mt][1] = (f32x4){0.f, 0.f, 0.f, 0.f};
  }
#pragma unroll
  for (int ks = 0; ks < 4; ++ks) {
    short8 bh0 = P1h[((2 * w + 0) * 4 + ks) * 64 + l];
    short8 bl0 = P1l[((2 * w + 0) * 4 + ks) * 64 + l];
    short8 bh1 = P1h[((2 * w + 1) * 4 + ks) * 64 + l];
    short8 bl1 = P1l[((2 * w + 1) * 4 + ks) * 64 + l];
#pragma unroll
    for (int mt = 0; mt < 4; ++mt) {
      short8 ah = *(const short8*)&Uh[(mt * 16 + lm) * 136 + ks * 32 + lk * 8];
      short8 al = *(const short8*)&Ul[(mt * 16 + lm) * 136 + ks * 32 + lk * 8];
      acc1[mt][0] = MFMA(ah, bh0, acc1[mt][0]);
      acc1[mt][0] = MFMA(al, bh0, acc1[mt][0]);
      acc1[mt][0] = MFMA(ah, bl0, acc1[mt][0]);
      acc1[mt][1] = MFMA(ah, bh1, acc1[mt][1]);
      acc1[mt][1] = MFMA(al, bh1, acc1[mt][1]);
      acc1[mt][1] = MFMA(ah, bl1, acc1[mt][1]);
    }
  }
  __syncthreads();  // all GEMM1 LDS reads done; overlay T onto U arena

  // ---- bias + write T (thread holds t[mt*16+lk*4+r][(2w+q)*16+lm])
#pragma unroll
  for (int q = 0; q < 2; ++q) {
    int h = (2 * w + q) * 16 + lm;
    float bnv = bn[h], bcv = bc[h];
#pragma unroll
    for (int mt = 0; mt < 4; ++mt) {
#pragma unroll
      for (int r = 0; r < 4; ++r) {
        int node = mt * 16 + lk * 4 + r;
        float t = acc1[mt][q][r] + bnv + ap[node] * bcv;
        Uh[node * 136 + h] = hi_u(t);
        Ul[node * 136 + h] = lo_u(t);
      }
    }
  }
  __syncthreads();

  // ---- GEMM2 (N-split): wave w -> o-tile w, all 4 m-tiles. K=128.
  f32x4 acc2[4];
#pragma unroll
  for (int mt = 0; mt < 4; ++mt) acc2[mt] = (f32x4){0.f, 0.f, 0.f, 0.f};
#pragma unroll
  for (int ks = 0; ks < 4; ++ks) {
    short8 bh = P2h[(w * 4 + ks) * 64 + l];
    short8 bl = P2l[(w * 4 + ks) * 64 + l];
#pragma unroll
    for (int mt = 0; mt < 4; ++mt) {
      short8 ah = *(const short8*)&Uh[(mt * 16 + lm) * 136 + ks * 32 + lk * 8];
      short8 al = *(const short8*)&Ul[(mt * 16 + lm) * 136 + ks * 32 + lk * 8];
      acc2[mt] = MFMA(ah, bh, acc2[mt]);
      acc2[mt] = MFMA(al, bh, acc2[mt]);
      acc2[mt] = MFMA(ah, bl, acc2[mt]);
    }
  }
  __syncthreads();  // T dead; V may overlay arena

  float buv = bu[w * 16 + lm];  // thread's upd column o = w*16+lm

  // ---- two 32-node halves: transform -> V, KAN GEMM, store
#pragma unroll
  for (int half = 0; half < 2; ++half) {
    // transform this half's upd values (mt = 2*half, 2*half+1) and write V
#pragma unroll
    for (int ms = 0; ms < 2; ++ms) {
      int mt = half * 2 + ms;
#pragma unroll
      for (int r = 0; r < 4; ++r) {
        float xv = acc2[mt][r] + buv;
        float sil = xv / (1.f + __expf(-xv));
        float b0[7], b1[6], b2[5];
#pragma unroll
        for (int q = 0; q < 7; ++q) b0[q] = (xv >= g[q] && xv < g[q + 1]) ? 1.f : 0.f;
#pragma unroll
        for (int q = 0; q < 6; ++q)
          b1[q] = (xv - g[q]) * r1[q] * b0[q] + (g[q + 2] - xv) * r1[q + 1] * b0[q + 1];
#pragma unroll
        for (int q = 0; q < 5; ++q)
          b2[q] = (xv - g[q]) * r2[q] * b1[q] + (g[q + 3] - xv) * r2[q + 1] * b1[q + 1];
        int ln = ms * 16 + lk * 4 + r;
        int base = ln * 392 + (w * 16 + lm) * 6;
        *(unsigned*)&Vh[base + 0] = pack_hi(sil, b2[0]);
        *(unsigned*)&Vh[base + 2] = pack_hi(b2[1], b2[2]);
        *(unsigned*)&Vh[base + 4] = pack_hi(b2[3], b2[4]);
        *(unsigned*)&Vl[base + 0] = pack_lo(sil, b2[0]);
        *(unsigned*)&Vl[base + 2] = pack_lo(b2[1], b2[2]);
        *(unsigned*)&Vl[base + 4] = pack_lo(b2[3], b2[4]);
      }
    }
    __syncthreads();

    // KAN GEMM (N-split): wave w -> o-tile w, 2 m-subtiles, K=384
    f32x4 accK[2];
    accK[0] = (f32x4){0.f, 0.f, 0.f, 0.f};
    accK[1] = (f32x4){0.f, 0.f, 0.f, 0.f};
#pragma unroll
    for (int ks = 0; ks < 12; ++ks) {
      short8 bh = P3h[(w * 12 + ks) * 64 + l];
      short8 bl = P3l[(w * 12 + ks) * 64 + l];
#pragma unroll
      for (int s = 0; s < 2; ++s) {
        short8 ah = *(const short8*)&Vh[(s * 16 + lm) * 392 + ks * 32 + lk * 8];
        short8 al = *(const short8*)&Vl[(s * 16 + lm) * 392 + ks * 32 + lk * 8];
        accK[s] = MFMA(ah, bh, accK[s]);
        accK[s] = MFMA(al, bh, accK[s]);
        accK[s] = MFMA(ah, bl, accK[s]);
      }
    }
    __syncthreads();  // V reads done (next half may overwrite)

    // store this half's out tile, deg fallback
#pragma unroll
    for (int s = 0; s < 2; ++s) {
      int o = w * 16 + lm;
#pragma unroll
      for (int r = 0; r < 4; ++r) {
        int node = half * 32 + s * 16 + lk * 4 + r;
        int n = n0 + node;
        if (n < NN) {
          float val = accK[s][r];
          if (degl[node] <= 0.f) val = x[(size_t)n * 64 + o];
          out[(size_t)n * 64 + o] = val;
        }
      }
    }
  }
}

extern "C" void kernel_launch(void* const* d_in, const int* in_sizes, int n_in,
                              void* d_out, int out_size, void* d_ws, size_t ws_size,
                              hipStream_t stream) {
  const float* x        = (const float*)d_in[0];
  const float* contexts = (const float*)d_in[1];
  const float* attn     = (const float*)d_in[2];
  const int*   seg      = (const int*)d_in[3];
  const float* Wn       = (const float*)d_in[4];
  const float* bn       = (const float*)d_in[5];
  const float* Wc       = (const float*)d_in[6];
  const float* bc       = (const float*)d_in[7];
  const float* Wu       = (const float*)d_in[8];
  const float* bu       = (const float*)d_in[9];
  const float* base_w   = (const float*)d_in[10];
  const float* spline_w = (const float*)d_in[11];
  const float* scaler   = (const float*)d_in[12];
  const float* gridp    = (const float*)d_in[13];
  float* out = (float*)d_out;

  float* ws     = (float*)d_ws;
  float* Sp     = ws;                    // 3,200,000
  float* aprime = Sp + 3200000;          // 50,000
  float* degw   = aprime + 50000;        // 50,000
  ushort_t* p1h = (ushort_t*)(degw + 50000);  // 16384
  ushort_t* p1l = p1h + 16384;
  ushort_t* p2h = p1l + 16384;           // 8192
  ushort_t* p2l = p2h + 8192;
  ushort_t* p3h = p2l + 8192;            // 24576
  ushort_t* p3l = p3h + 24576;
  int* off      = (int*)(p3l + 24576);   // 50,001

  kA_pack_off<<<3125, 256, 0, stream>>>(Wn, Wc, Wu, base_w, spline_w, scaler, seg,
                                        p1h, p1l, p2h, p2l, p3h, p3l, off);
  k1_edge_agg<<<12500, 256, 0, stream>>>(contexts, attn, off, Sp, aprime, degw);
  k234<<<782, 256, 0, stream>>>(x, Sp, aprime, degw, bn, bc, bu,
                                p1h, p1l, p2h, p2l, p3h, p3l, gridp, out);
}